// Round 1
// 838.453 us; speedup vs baseline: 1.1032x; 1.1032x over previous
//
#include <hip/hip_runtime.h>

#define DHW (128*128*128)

// Kernel 1: per-batch rotation matrix from im_feat @ pos_w.T + pos_b.
// R = rot_y(mu) @ rot_x(rho) =
//   [ cm,  sm*sr, -sm*cr ]
//   [ 0,   cr,     sr    ]
//   [ sm, -cm*sr,  cm*cr ]
__global__ void compute_R_kernel(const float* __restrict__ im_feat,
                                 const float* __restrict__ pos_w,
                                 const float* __restrict__ pos_b,
                                 float* __restrict__ Rout) {
    int b = blockIdx.x;
    int t = threadIdx.x;
    const float* f = im_feat + b * 512;
    float s0 = 0.f, s1 = 0.f;
    for (int i = t; i < 512; i += 64) {
        float v = f[i];
        s0 = fmaf(v, pos_w[i], s0);        // row 0 -> mu
        s1 = fmaf(v, pos_w[512 + i], s1);  // row 1 -> rho
    }
    for (int off = 32; off > 0; off >>= 1) {
        s0 += __shfl_down(s0, off, 64);
        s1 += __shfl_down(s1, off, 64);
    }
    if (t == 0) {
        float mu  = s0 + pos_b[0];
        float rho = s1 + pos_b[1];
        float cm = cosf(mu),  sm = sinf(mu);
        float cr = cosf(rho), sr = sinf(rho);
        float* R = Rout + b * 16;
        R[0] = cm;   R[1] = sm * sr;  R[2] = -sm * cr;
        R[3] = 0.f;  R[4] = cr;       R[5] = sr;
        R[6] = sm;   R[7] = -cm * sr; R[8] = cm * cr;
    }
}

// Kernel 2: one thread per (b,d,h,w); trilinear sample of 4 channels.
// This revision: (a) batch index derived from blockIdx -> scalar (SGPR) base
// pointers, 32-bit per-lane offsets; (b) ALL 32 gather loads issued into
// registers before any consumption (MLP 8 -> 32 outstanding); (c) whole-sample
// out-of-bounds early-out (no loads for fully-OOB lanes); (d) non-temporal
// output stores (streaming, never re-read).
__global__ __launch_bounds__(256) void sample_kernel(const float* __restrict__ x,
                                                     const float* __restrict__ Rin,
                                                     float* __restrict__ out) {
    unsigned bid = blockIdx.x;
    int b = (int)(bid >> 13);                       // 8192 blocks per batch: block-uniform
    unsigned spatial = ((bid & 8191u) << 8) | threadIdx.x;

    int w = spatial & 127;
    int h = (spatial >> 7) & 127;
    int d = spatial >> 14;

    const float* R = Rin + b * 16;
    const float step = 2.0f / 127.0f;
    float X = fmaf((float)w, step, -1.0f);
    float Y = fmaf((float)h, step, -1.0f);
    float Z = fmaf((float)d, step, -1.0f);

    // grid = R @ (X,Y,Z); R[3] == 0
    float gx = fmaf(R[0], X, fmaf(R[1], Y, R[2] * Z));
    float gy = fmaf(R[4], Y, R[5] * Z);
    float gz = fmaf(R[6], X, fmaf(R[7], Y, R[8] * Z));

    // unnormalize, align_corners=False: ix = ((g+1)*128 - 1)/2 = g*64 + 63.5
    float ix = fmaf(gx, 64.0f, 63.5f);
    float iy = fmaf(gy, 64.0f, 63.5f);
    float iz = fmaf(gz, 64.0f, 63.5f);

    float fx0 = floorf(ix), fy0 = floorf(iy), fz0 = floorf(iz);
    float fx = ix - fx0, fy = iy - fy0, fz = iz - fz0;
    int ix0 = (int)fx0, iy0 = (int)fy0, iz0 = (int)fz0;
    int ix1 = ix0 + 1, iy1 = iy0 + 1, iz1 = iz0 + 1;

    // validity folded into per-axis weights (zero padding)
    float wx0 = ((unsigned)ix0 < 128u) ? (1.f - fx) : 0.f;
    float wx1 = ((unsigned)ix1 < 128u) ? fx : 0.f;
    float wy0 = ((unsigned)iy0 < 128u) ? (1.f - fy) : 0.f;
    float wy1 = ((unsigned)iy1 < 128u) ? fy : 0.f;
    float wz0 = ((unsigned)iz0 < 128u) ? (1.f - fz) : 0.f;
    float wz1 = ((unsigned)iz1 < 128u) ? fz : 0.f;

    float* ob = out + (size_t)(b << 2) * DHW + spatial;

    // whole-sample OOB: all 8 weights zero -> write zeros, no gathers.
    if ((wx0 + wx1) * (wy0 + wy1) * (wz0 + wz1) == 0.f) {
        __builtin_nontemporal_store(0.f, ob);
        __builtin_nontemporal_store(0.f, ob + DHW);
        __builtin_nontemporal_store(0.f, ob + 2 * DHW);
        __builtin_nontemporal_store(0.f, ob + 3 * DHW);
        return;
    }

    // clamped indices (loads always in-bounds; zero weight kills invalid)
    int xc0 = min(max(ix0, 0), 127), xc1 = min(max(ix1, 0), 127);
    int yc0 = min(max(iy0, 0), 127), yc1 = min(max(iy1, 0), 127);
    int zc0 = min(max(iz0, 0), 127), zc1 = min(max(iz1, 0), 127);

    int r00 = (zc0 * 128 + yc0) * 128;  // z0,y0
    int r01 = (zc0 * 128 + yc1) * 128;  // z0,y1
    int r10 = (zc1 * 128 + yc0) * 128;  // z1,y0
    int r11 = (zc1 * 128 + yc1) * 128;  // z1,y1

    int o0 = r00 + xc0, o1 = r00 + xc1;
    int o2 = r01 + xc0, o3 = r01 + xc1;
    int o4 = r10 + xc0, o5 = r10 + xc1;
    int o6 = r11 + xc0, o7 = r11 + xc1;

    const float* xb = x + (size_t)(b << 2) * DHW;   // scalar base (b is SGPR)

    // Issue ALL 32 gathers before consuming any -> 32 outstanding loads/wave.
    float v[4][8];
#pragma unroll
    for (int c = 0; c < 4; ++c) {
        const float* xc = xb + (size_t)c * DHW;
        v[c][0] = xc[o0]; v[c][1] = xc[o1];
        v[c][2] = xc[o2]; v[c][3] = xc[o3];
        v[c][4] = xc[o4]; v[c][5] = xc[o5];
        v[c][6] = xc[o6]; v[c][7] = xc[o7];
    }

    float w00 = wz0 * wy0, w01 = wz0 * wy1, w10 = wz1 * wy0, w11 = wz1 * wy1;

#pragma unroll
    for (int c = 0; c < 4; ++c) {
        float acc;
        acc  = (v[c][0] * wx0 + v[c][1] * wx1) * w00;
        acc += (v[c][2] * wx0 + v[c][3] * wx1) * w01;
        acc += (v[c][4] * wx0 + v[c][5] * wx1) * w10;
        acc += (v[c][6] * wx0 + v[c][7] * wx1) * w11;
        __builtin_nontemporal_store(acc, ob + (size_t)c * DHW);
    }
}

extern "C" void kernel_launch(void* const* d_in, const int* in_sizes, int n_in,
                              void* d_out, int out_size, void* d_ws, size_t ws_size,
                              hipStream_t stream) {
    const float* x       = (const float*)d_in[0];
    const float* im_feat = (const float*)d_in[1];
    const float* pos_w   = (const float*)d_in[2];
    const float* pos_b   = (const float*)d_in[3];
    float* out = (float*)d_out;
    float* Rws = (float*)d_ws;

    compute_R_kernel<<<8, 64, 0, stream>>>(im_feat, pos_w, pos_b, Rws);
    int total = 8 * DHW;
    sample_kernel<<<total / 256, 256, 0, stream>>>(x, Rws, out);
}

// Round 2
// 639.839 us; speedup vs baseline: 1.4457x; 1.3104x over previous
//
#include <hip/hip_runtime.h>

#define DHW (128*128*128)

// Kernel 1: per-batch rotation matrix from im_feat @ pos_w.T + pos_b.
// R = rot_y(mu) @ rot_x(rho) =
//   [ cm,  sm*sr, -sm*cr ]
//   [ 0,   cr,     sr    ]
//   [ sm, -cm*sr,  cm*cr ]
__global__ void compute_R_kernel(const float* __restrict__ im_feat,
                                 const float* __restrict__ pos_w,
                                 const float* __restrict__ pos_b,
                                 float* __restrict__ Rout) {
    int b = blockIdx.x;
    int t = threadIdx.x;
    const float* f = im_feat + b * 512;
    float s0 = 0.f, s1 = 0.f;
    for (int i = t; i < 512; i += 64) {
        float v = f[i];
        s0 = fmaf(v, pos_w[i], s0);        // row 0 -> mu
        s1 = fmaf(v, pos_w[512 + i], s1);  // row 1 -> rho
    }
    for (int off = 32; off > 0; off >>= 1) {
        s0 += __shfl_down(s0, off, 64);
        s1 += __shfl_down(s1, off, 64);
    }
    if (t == 0) {
        float mu  = s0 + pos_b[0];
        float rho = s1 + pos_b[1];
        float cm = cosf(mu),  sm = sinf(mu);
        float cr = cosf(rho), sr = sinf(rho);
        float* R = Rout + b * 16;
        R[0] = cm;   R[1] = sm * sr;  R[2] = -sm * cr;
        R[3] = 0.f;  R[4] = cr;       R[5] = sr;
        R[6] = sm;   R[7] = -cm * sr; R[8] = cm * cr;
    }
}

// Kernel T: transpose x[B,C,DHW] -> xt[B,DHW,C] (channel-interleaved float4).
// Both sides fully coalesced: 4 stride-DHW coalesced reads, one float4 store.
__global__ __launch_bounds__(256) void transpose_kernel(const float* __restrict__ x,
                                                        float4* __restrict__ xt) {
    unsigned tid = blockIdx.x * 256u + threadIdx.x;
    unsigned spatial = tid & (DHW - 1u);
    unsigned b = tid >> 21;
    const float* xb = x + (size_t)(b << 2) * DHW;
    float a0 = xb[spatial];
    float a1 = xb[spatial + DHW];
    float a2 = xb[spatial + 2u * DHW];
    float a3 = xb[spatial + 3u * DHW];
    xt[(size_t)tid] = make_float4(a0, a1, a2, a3);
}

// Kernel 2 (transposed path): one thread per (b,d,h,w). Each trilinear corner
// is ONE aligned float4 gather (all 4 channels) -> 8 gathers/thread instead of
// 32, ~4x fewer L1 line-transactions (the measured bottleneck).
__global__ __launch_bounds__(256) void sample_kernel_t(const float4* __restrict__ xt,
                                                       const float* __restrict__ Rin,
                                                       float* __restrict__ out) {
    unsigned bid = blockIdx.x;
    int b = (int)(bid >> 13);                       // block-uniform batch
    unsigned spatial = ((bid & 8191u) << 8) | threadIdx.x;

    int w = spatial & 127;
    int h = (spatial >> 7) & 127;
    int d = spatial >> 14;

    const float* R = Rin + b * 16;
    const float step = 2.0f / 127.0f;
    float X = fmaf((float)w, step, -1.0f);
    float Y = fmaf((float)h, step, -1.0f);
    float Z = fmaf((float)d, step, -1.0f);

    float gx = fmaf(R[0], X, fmaf(R[1], Y, R[2] * Z));
    float gy = fmaf(R[4], Y, R[5] * Z);
    float gz = fmaf(R[6], X, fmaf(R[7], Y, R[8] * Z));

    float ix = fmaf(gx, 64.0f, 63.5f);
    float iy = fmaf(gy, 64.0f, 63.5f);
    float iz = fmaf(gz, 64.0f, 63.5f);

    float fx0 = floorf(ix), fy0 = floorf(iy), fz0 = floorf(iz);
    float fx = ix - fx0, fy = iy - fy0, fz = iz - fz0;
    int ix0 = (int)fx0, iy0 = (int)fy0, iz0 = (int)fz0;
    int ix1 = ix0 + 1, iy1 = iy0 + 1, iz1 = iz0 + 1;

    float wx0 = ((unsigned)ix0 < 128u) ? (1.f - fx) : 0.f;
    float wx1 = ((unsigned)ix1 < 128u) ? fx : 0.f;
    float wy0 = ((unsigned)iy0 < 128u) ? (1.f - fy) : 0.f;
    float wy1 = ((unsigned)iy1 < 128u) ? fy : 0.f;
    float wz0 = ((unsigned)iz0 < 128u) ? (1.f - fz) : 0.f;
    float wz1 = ((unsigned)iz1 < 128u) ? fz : 0.f;

    float* ob = out + (size_t)(b << 2) * DHW + spatial;

    if ((wx0 + wx1) * (wy0 + wy1) * (wz0 + wz1) == 0.f) {
        __builtin_nontemporal_store(0.f, ob);
        __builtin_nontemporal_store(0.f, ob + DHW);
        __builtin_nontemporal_store(0.f, ob + 2 * DHW);
        __builtin_nontemporal_store(0.f, ob + 3 * DHW);
        return;
    }

    int xc0 = min(max(ix0, 0), 127), xc1 = min(max(ix1, 0), 127);
    int yc0 = min(max(iy0, 0), 127), yc1 = min(max(iy1, 0), 127);
    int zc0 = min(max(iz0, 0), 127), zc1 = min(max(iz1, 0), 127);

    int r00 = (zc0 * 128 + yc0) * 128;
    int r01 = (zc0 * 128 + yc1) * 128;
    int r10 = (zc1 * 128 + yc0) * 128;
    int r11 = (zc1 * 128 + yc1) * 128;

    const float4* xb = xt + (size_t)b * DHW;   // scalar base (b is SGPR)

    // Issue all 8 float4 gathers before consuming any.
    float4 q0 = xb[r00 + xc0], q1 = xb[r00 + xc1];
    float4 q2 = xb[r01 + xc0], q3 = xb[r01 + xc1];
    float4 q4 = xb[r10 + xc0], q5 = xb[r10 + xc1];
    float4 q6 = xb[r11 + xc0], q7 = xb[r11 + xc1];

    float w00 = wz0 * wy0, w01 = wz0 * wy1, w10 = wz1 * wy0, w11 = wz1 * wy1;

    float a0, a1, a2, a3;
    a0 = (q0.x * wx0 + q1.x * wx1) * w00;
    a1 = (q0.y * wx0 + q1.y * wx1) * w00;
    a2 = (q0.z * wx0 + q1.z * wx1) * w00;
    a3 = (q0.w * wx0 + q1.w * wx1) * w00;

    a0 = fmaf(q2.x * wx0 + q3.x * wx1, w01, a0);
    a1 = fmaf(q2.y * wx0 + q3.y * wx1, w01, a1);
    a2 = fmaf(q2.z * wx0 + q3.z * wx1, w01, a2);
    a3 = fmaf(q2.w * wx0 + q3.w * wx1, w01, a3);

    a0 = fmaf(q4.x * wx0 + q5.x * wx1, w10, a0);
    a1 = fmaf(q4.y * wx0 + q5.y * wx1, w10, a1);
    a2 = fmaf(q4.z * wx0 + q5.z * wx1, w10, a2);
    a3 = fmaf(q4.w * wx0 + q5.w * wx1, w10, a3);

    a0 = fmaf(q6.x * wx0 + q7.x * wx1, w11, a0);
    a1 = fmaf(q6.y * wx0 + q7.y * wx1, w11, a1);
    a2 = fmaf(q6.z * wx0 + q7.z * wx1, w11, a2);
    a3 = fmaf(q6.w * wx0 + q7.w * wx1, w11, a3);

    __builtin_nontemporal_store(a0, ob);
    __builtin_nontemporal_store(a1, ob + DHW);
    __builtin_nontemporal_store(a2, ob + 2 * DHW);
    __builtin_nontemporal_store(a3, ob + 3 * DHW);
}

// Fallback (verified R1 kernel): direct gather from [B,C,DHW] layout.
__global__ __launch_bounds__(256) void sample_kernel(const float* __restrict__ x,
                                                     const float* __restrict__ Rin,
                                                     float* __restrict__ out) {
    unsigned bid = blockIdx.x;
    int b = (int)(bid >> 13);
    unsigned spatial = ((bid & 8191u) << 8) | threadIdx.x;

    int w = spatial & 127;
    int h = (spatial >> 7) & 127;
    int d = spatial >> 14;

    const float* R = Rin + b * 16;
    const float step = 2.0f / 127.0f;
    float X = fmaf((float)w, step, -1.0f);
    float Y = fmaf((float)h, step, -1.0f);
    float Z = fmaf((float)d, step, -1.0f);

    float gx = fmaf(R[0], X, fmaf(R[1], Y, R[2] * Z));
    float gy = fmaf(R[4], Y, R[5] * Z);
    float gz = fmaf(R[6], X, fmaf(R[7], Y, R[8] * Z));

    float ix = fmaf(gx, 64.0f, 63.5f);
    float iy = fmaf(gy, 64.0f, 63.5f);
    float iz = fmaf(gz, 64.0f, 63.5f);

    float fx0 = floorf(ix), fy0 = floorf(iy), fz0 = floorf(iz);
    float fx = ix - fx0, fy = iy - fy0, fz = iz - fz0;
    int ix0 = (int)fx0, iy0 = (int)fy0, iz0 = (int)fz0;
    int ix1 = ix0 + 1, iy1 = iy0 + 1, iz1 = iz0 + 1;

    float wx0 = ((unsigned)ix0 < 128u) ? (1.f - fx) : 0.f;
    float wx1 = ((unsigned)ix1 < 128u) ? fx : 0.f;
    float wy0 = ((unsigned)iy0 < 128u) ? (1.f - fy) : 0.f;
    float wy1 = ((unsigned)iy1 < 128u) ? fy : 0.f;
    float wz0 = ((unsigned)iz0 < 128u) ? (1.f - fz) : 0.f;
    float wz1 = ((unsigned)iz1 < 128u) ? fz : 0.f;

    float* ob = out + (size_t)(b << 2) * DHW + spatial;

    if ((wx0 + wx1) * (wy0 + wy1) * (wz0 + wz1) == 0.f) {
        __builtin_nontemporal_store(0.f, ob);
        __builtin_nontemporal_store(0.f, ob + DHW);
        __builtin_nontemporal_store(0.f, ob + 2 * DHW);
        __builtin_nontemporal_store(0.f, ob + 3 * DHW);
        return;
    }

    int xc0 = min(max(ix0, 0), 127), xc1 = min(max(ix1, 0), 127);
    int yc0 = min(max(iy0, 0), 127), yc1 = min(max(iy1, 0), 127);
    int zc0 = min(max(iz0, 0), 127), zc1 = min(max(iz1, 0), 127);

    int r00 = (zc0 * 128 + yc0) * 128;
    int r01 = (zc0 * 128 + yc1) * 128;
    int r10 = (zc1 * 128 + yc0) * 128;
    int r11 = (zc1 * 128 + yc1) * 128;

    int o0 = r00 + xc0, o1 = r00 + xc1;
    int o2 = r01 + xc0, o3 = r01 + xc1;
    int o4 = r10 + xc0, o5 = r10 + xc1;
    int o6 = r11 + xc0, o7 = r11 + xc1;

    const float* xb = x + (size_t)(b << 2) * DHW;

    float v[4][8];
#pragma unroll
    for (int c = 0; c < 4; ++c) {
        const float* xc = xb + (size_t)c * DHW;
        v[c][0] = xc[o0]; v[c][1] = xc[o1];
        v[c][2] = xc[o2]; v[c][3] = xc[o3];
        v[c][4] = xc[o4]; v[c][5] = xc[o5];
        v[c][6] = xc[o6]; v[c][7] = xc[o7];
    }

    float w00 = wz0 * wy0, w01 = wz0 * wy1, w10 = wz1 * wy0, w11 = wz1 * wy1;

#pragma unroll
    for (int c = 0; c < 4; ++c) {
        float acc;
        acc  = (v[c][0] * wx0 + v[c][1] * wx1) * w00;
        acc += (v[c][2] * wx0 + v[c][3] * wx1) * w01;
        acc += (v[c][4] * wx0 + v[c][5] * wx1) * w10;
        acc += (v[c][6] * wx0 + v[c][7] * wx1) * w11;
        __builtin_nontemporal_store(acc, ob + (size_t)c * DHW);
    }
}

extern "C" void kernel_launch(void* const* d_in, const int* in_sizes, int n_in,
                              void* d_out, int out_size, void* d_ws, size_t ws_size,
                              hipStream_t stream) {
    const float* x       = (const float*)d_in[0];
    const float* im_feat = (const float*)d_in[1];
    const float* pos_w   = (const float*)d_in[2];
    const float* pos_b   = (const float*)d_in[3];
    float* out = (float*)d_out;

    float* Rws = (float*)d_ws;                       // 8 * 16 floats
    const size_t XT_OFF = 1024;                      // bytes; keeps xt 16B-aligned
    size_t need = XT_OFF + (size_t)8 * 4 * DHW * sizeof(float);

    compute_R_kernel<<<8, 64, 0, stream>>>(im_feat, pos_w, pos_b, Rws);

    int total = 8 * DHW;
    if (ws_size >= need) {
        float4* xt = (float4*)((char*)d_ws + XT_OFF);
        transpose_kernel<<<total / 256, 256, 0, stream>>>(x, xt);
        sample_kernel_t<<<total / 256, 256, 0, stream>>>(xt, Rws, out);
    } else {
        sample_kernel<<<total / 256, 256, 0, stream>>>(x, Rws, out);
    }
}

// Round 3
// 536.625 us; speedup vs baseline: 1.7238x; 1.1923x over previous
//
#include <hip/hip_runtime.h>
#include <hip/hip_fp16.h>

#define DHW (128*128*128)

typedef unsigned int u32x4 __attribute__((ext_vector_type(4)));

// Kernel 1: per-batch rotation matrix from im_feat @ pos_w.T + pos_b.
// R = rot_y(mu) @ rot_x(rho) =
//   [ cm,  sm*sr, -sm*cr ]
//   [ 0,   cr,     sr    ]
//   [ sm, -cm*sr,  cm*cr ]
__global__ void compute_R_kernel(const float* __restrict__ im_feat,
                                 const float* __restrict__ pos_w,
                                 const float* __restrict__ pos_b,
                                 float* __restrict__ Rout) {
    int b = blockIdx.x;
    int t = threadIdx.x;
    const float* f = im_feat + b * 512;
    float s0 = 0.f, s1 = 0.f;
    for (int i = t; i < 512; i += 64) {
        float v = f[i];
        s0 = fmaf(v, pos_w[i], s0);        // row 0 -> mu
        s1 = fmaf(v, pos_w[512 + i], s1);  // row 1 -> rho
    }
    for (int off = 32; off > 0; off >>= 1) {
        s0 += __shfl_down(s0, off, 64);
        s1 += __shfl_down(s1, off, 64);
    }
    if (t == 0) {
        float mu  = s0 + pos_b[0];
        float rho = s1 + pos_b[1];
        float cm = cosf(mu),  sm = sinf(mu);
        float cr = cosf(rho), sr = sinf(rho);
        float* R = Rout + b * 16;
        R[0] = cm;   R[1] = sm * sr;  R[2] = -sm * cr;
        R[3] = 0.f;  R[4] = cr;       R[5] = sr;
        R[6] = sm;   R[7] = -cm * sr; R[8] = cm * cr;
    }
}

// Kernel T: x[B,C,DHW] fp32 -> xt[B,DHW] of 4xfp16 (8 B/texel, RTN).
__global__ __launch_bounds__(256) void transpose_pack_kernel(const float* __restrict__ x,
                                                             uint2* __restrict__ xt) {
    unsigned tid = blockIdx.x * 256u + threadIdx.x;
    unsigned spatial = tid & (DHW - 1u);
    unsigned b = tid >> 21;
    const float* xb = x + (size_t)(b << 2) * DHW + spatial;
    float a0 = xb[0];
    float a1 = xb[DHW];
    float a2 = xb[2u * DHW];
    float a3 = xb[3u * DHW];
    unsigned lo = (unsigned)__half_as_ushort(__float2half_rn(a0)) |
                  ((unsigned)__half_as_ushort(__float2half_rn(a1)) << 16);
    unsigned hi = (unsigned)__half_as_ushort(__float2half_rn(a2)) |
                  ((unsigned)__half_as_ushort(__float2half_rn(a3)) << 16);
    xt[(size_t)tid] = make_uint2(lo, hi);
}

__device__ inline float2 up2(unsigned u) {
    __half2 h = reinterpret_cast<const __half2&>(u);
    return __half22float2(h);
}

// Kernel 2 (fp16-packed path): one thread per (b,d,h,w).
// Each (z,y) corner-pair is ONE 16 B gather covering all 4 channels at BOTH
// x-corners -> 4 gather instructions/thread (was 8). TA-transaction bound.
__global__ __launch_bounds__(256) void sample_kernel_h(const char* __restrict__ xt,
                                                       const float* __restrict__ Rin,
                                                       float* __restrict__ out) {
    unsigned bid = blockIdx.x;
    int b = (int)(bid >> 13);                        // block-uniform batch
    unsigned spatial = ((bid & 8191u) << 8) | threadIdx.x;

    int w = spatial & 127;
    int h = (spatial >> 7) & 127;
    int d = spatial >> 14;
    // h and d are wave-uniform under this mapping -> scalarize.
    h = __builtin_amdgcn_readfirstlane(h);
    d = __builtin_amdgcn_readfirstlane(d);

    const float* R = Rin + b * 16;
    const float step = 2.0f / 127.0f;
    float X = fmaf((float)w, step, -1.0f);
    float Y = fmaf((float)h, step, -1.0f);
    float Z = fmaf((float)d, step, -1.0f);

    float gx = fmaf(R[0], X, fmaf(R[1], Y, R[2] * Z));
    float gy = fmaf(R[4], Y, R[5] * Z);              // uniform per wave
    float gz = fmaf(R[6], X, fmaf(R[7], Y, R[8] * Z));

    float ix = fmaf(gx, 64.0f, 63.5f);
    float iy = fmaf(gy, 64.0f, 63.5f);
    float iz = fmaf(gz, 64.0f, 63.5f);

    float fx0 = floorf(ix), fy0 = floorf(iy), fz0 = floorf(iz);
    float fx = ix - fx0, fy = iy - fy0, fz = iz - fz0;
    int ix0 = (int)fx0, iy0 = (int)fy0, iz0 = (int)fz0;
    int ix1 = ix0 + 1, iy1 = iy0 + 1, iz1 = iz0 + 1;

    float wx0 = ((unsigned)ix0 < 128u) ? (1.f - fx) : 0.f;
    float wx1 = ((unsigned)ix1 < 128u) ? fx : 0.f;
    float wy0 = ((unsigned)iy0 < 128u) ? (1.f - fy) : 0.f;
    float wy1 = ((unsigned)iy1 < 128u) ? fy : 0.f;
    float wz0 = ((unsigned)iz0 < 128u) ? (1.f - fz) : 0.f;
    float wz1 = ((unsigned)iz1 < 128u) ? fz : 0.f;

    float* ob = out + (size_t)(b << 2) * DHW + spatial;

    // whole-sample OOB: write zeros, no gathers.
    if ((wx0 + wx1) * (wy0 + wy1) * (wz0 + wz1) == 0.f) {
        __builtin_nontemporal_store(0.f, ob);
        __builtin_nontemporal_store(0.f, ob + DHW);
        __builtin_nontemporal_store(0.f, ob + 2 * DHW);
        __builtin_nontemporal_store(0.f, ob + 3 * DHW);
        return;
    }
    // Past the early-out, wx0+wx1 > 0 implies ix0 in [-1,127].

    int yc0 = min(max(iy0, 0), 127), yc1 = min(max(iy1, 0), 127);
    int zc0 = min(max(iz0, 0), 127), zc1 = min(max(iz1, 0), 127);

    // x window base: texels {base, base+1} always in-row, 8B-aligned.
    int base = min(max(ix0, 0), 126);
    // per-slot x weights (never multiplies garbage; clamp cases remapped)
    float sw0 = (base == ix0 ? wx0 : 0.f) + (base == ix1 ? wx1 : 0.f);
    float sw1 = (base + 1 == ix0 ? wx0 : 0.f) + (base + 1 == ix1 ? wx1 : 0.f);

    const char* xb = xt + (size_t)b * (DHW * 8);
    unsigned o00 = (((unsigned)(zc0 * 128 + yc0) << 7) + (unsigned)base) << 3;
    unsigned o01 = (((unsigned)(zc0 * 128 + yc1) << 7) + (unsigned)base) << 3;
    unsigned o10 = (((unsigned)(zc1 * 128 + yc0) << 7) + (unsigned)base) << 3;
    unsigned o11 = (((unsigned)(zc1 * 128 + yc1) << 7) + (unsigned)base) << 3;

    u32x4 q0, q1, q2, q3;
    asm volatile("global_load_dwordx4 %0, %1, off" : "=v"(q0) : "v"(xb + o00));
    asm volatile("global_load_dwordx4 %0, %1, off" : "=v"(q1) : "v"(xb + o01));
    asm volatile("global_load_dwordx4 %0, %1, off" : "=v"(q2) : "v"(xb + o10));
    asm volatile("global_load_dwordx4 %0, %1, off" : "=v"(q3) : "v"(xb + o11));
    asm volatile("s_waitcnt vmcnt(0)" ::: "memory");
    __builtin_amdgcn_sched_barrier(0);

    float w00 = wz0 * wy0, w01 = wz0 * wy1, w10 = wz1 * wy0, w11 = wz1 * wy1;

    float a0 = 0.f, a1 = 0.f, a2 = 0.f, a3 = 0.f;
    {   // corner pair (z0,y0): q0 = {c01@s0, c23@s0, c01@s1, c23@s1}
        float ws0 = sw0 * w00, ws1 = sw1 * w00;
        float2 p0 = up2(q0.x), p1 = up2(q0.y), p2 = up2(q0.z), p3 = up2(q0.w);
        a0 = fmaf(p0.x, ws0, fmaf(p2.x, ws1, a0));
        a1 = fmaf(p0.y, ws0, fmaf(p2.y, ws1, a1));
        a2 = fmaf(p1.x, ws0, fmaf(p3.x, ws1, a2));
        a3 = fmaf(p1.y, ws0, fmaf(p3.y, ws1, a3));
    }
    {   // (z0,y1)
        float ws0 = sw0 * w01, ws1 = sw1 * w01;
        float2 p0 = up2(q1.x), p1 = up2(q1.y), p2 = up2(q1.z), p3 = up2(q1.w);
        a0 = fmaf(p0.x, ws0, fmaf(p2.x, ws1, a0));
        a1 = fmaf(p0.y, ws0, fmaf(p2.y, ws1, a1));
        a2 = fmaf(p1.x, ws0, fmaf(p3.x, ws1, a2));
        a3 = fmaf(p1.y, ws0, fmaf(p3.y, ws1, a3));
    }
    {   // (z1,y0)
        float ws0 = sw0 * w10, ws1 = sw1 * w10;
        float2 p0 = up2(q2.x), p1 = up2(q2.y), p2 = up2(q2.z), p3 = up2(q2.w);
        a0 = fmaf(p0.x, ws0, fmaf(p2.x, ws1, a0));
        a1 = fmaf(p0.y, ws0, fmaf(p2.y, ws1, a1));
        a2 = fmaf(p1.x, ws0, fmaf(p3.x, ws1, a2));
        a3 = fmaf(p1.y, ws0, fmaf(p3.y, ws1, a3));
    }
    {   // (z1,y1)
        float ws0 = sw0 * w11, ws1 = sw1 * w11;
        float2 p0 = up2(q3.x), p1 = up2(q3.y), p2 = up2(q3.z), p3 = up2(q3.w);
        a0 = fmaf(p0.x, ws0, fmaf(p2.x, ws1, a0));
        a1 = fmaf(p0.y, ws0, fmaf(p2.y, ws1, a1));
        a2 = fmaf(p1.x, ws0, fmaf(p3.x, ws1, a2));
        a3 = fmaf(p1.y, ws0, fmaf(p3.y, ws1, a3));
    }

    __builtin_nontemporal_store(a0, ob);
    __builtin_nontemporal_store(a1, ob + DHW);
    __builtin_nontemporal_store(a2, ob + 2 * DHW);
    __builtin_nontemporal_store(a3, ob + 3 * DHW);
}

// Fallback (verified R1 kernel): direct fp32 gather from [B,C,DHW] layout.
__global__ __launch_bounds__(256) void sample_kernel(const float* __restrict__ x,
                                                     const float* __restrict__ Rin,
                                                     float* __restrict__ out) {
    unsigned bid = blockIdx.x;
    int b = (int)(bid >> 13);
    unsigned spatial = ((bid & 8191u) << 8) | threadIdx.x;

    int w = spatial & 127;
    int h = (spatial >> 7) & 127;
    int d = spatial >> 14;

    const float* R = Rin + b * 16;
    const float step = 2.0f / 127.0f;
    float X = fmaf((float)w, step, -1.0f);
    float Y = fmaf((float)h, step, -1.0f);
    float Z = fmaf((float)d, step, -1.0f);

    float gx = fmaf(R[0], X, fmaf(R[1], Y, R[2] * Z));
    float gy = fmaf(R[4], Y, R[5] * Z);
    float gz = fmaf(R[6], X, fmaf(R[7], Y, R[8] * Z));

    float ix = fmaf(gx, 64.0f, 63.5f);
    float iy = fmaf(gy, 64.0f, 63.5f);
    float iz = fmaf(gz, 64.0f, 63.5f);

    float fx0 = floorf(ix), fy0 = floorf(iy), fz0 = floorf(iz);
    float fx = ix - fx0, fy = iy - fy0, fz = iz - fz0;
    int ix0 = (int)fx0, iy0 = (int)fy0, iz0 = (int)fz0;
    int ix1 = ix0 + 1, iy1 = iy0 + 1, iz1 = iz0 + 1;

    float wx0 = ((unsigned)ix0 < 128u) ? (1.f - fx) : 0.f;
    float wx1 = ((unsigned)ix1 < 128u) ? fx : 0.f;
    float wy0 = ((unsigned)iy0 < 128u) ? (1.f - fy) : 0.f;
    float wy1 = ((unsigned)iy1 < 128u) ? fy : 0.f;
    float wz0 = ((unsigned)iz0 < 128u) ? (1.f - fz) : 0.f;
    float wz1 = ((unsigned)iz1 < 128u) ? fz : 0.f;

    float* ob = out + (size_t)(b << 2) * DHW + spatial;

    if ((wx0 + wx1) * (wy0 + wy1) * (wz0 + wz1) == 0.f) {
        __builtin_nontemporal_store(0.f, ob);
        __builtin_nontemporal_store(0.f, ob + DHW);
        __builtin_nontemporal_store(0.f, ob + 2 * DHW);
        __builtin_nontemporal_store(0.f, ob + 3 * DHW);
        return;
    }

    int xc0 = min(max(ix0, 0), 127), xc1 = min(max(ix1, 0), 127);
    int yc0 = min(max(iy0, 0), 127), yc1 = min(max(iy1, 0), 127);
    int zc0 = min(max(iz0, 0), 127), zc1 = min(max(iz1, 0), 127);

    int r00 = (zc0 * 128 + yc0) * 128;
    int r01 = (zc0 * 128 + yc1) * 128;
    int r10 = (zc1 * 128 + yc0) * 128;
    int r11 = (zc1 * 128 + yc1) * 128;

    int o0 = r00 + xc0, o1 = r00 + xc1;
    int o2 = r01 + xc0, o3 = r01 + xc1;
    int o4 = r10 + xc0, o5 = r10 + xc1;
    int o6 = r11 + xc0, o7 = r11 + xc1;

    const float* xb = x + (size_t)(b << 2) * DHW;

    float v[4][8];
#pragma unroll
    for (int c = 0; c < 4; ++c) {
        const float* xc = xb + (size_t)c * DHW;
        v[c][0] = xc[o0]; v[c][1] = xc[o1];
        v[c][2] = xc[o2]; v[c][3] = xc[o3];
        v[c][4] = xc[o4]; v[c][5] = xc[o5];
        v[c][6] = xc[o6]; v[c][7] = xc[o7];
    }

    float w00 = wz0 * wy0, w01 = wz0 * wy1, w10 = wz1 * wy0, w11 = wz1 * wy1;

#pragma unroll
    for (int c = 0; c < 4; ++c) {
        float acc;
        acc  = (v[c][0] * wx0 + v[c][1] * wx1) * w00;
        acc += (v[c][2] * wx0 + v[c][3] * wx1) * w01;
        acc += (v[c][4] * wx0 + v[c][5] * wx1) * w10;
        acc += (v[c][6] * wx0 + v[c][7] * wx1) * w11;
        __builtin_nontemporal_store(acc, ob + (size_t)c * DHW);
    }
}

extern "C" void kernel_launch(void* const* d_in, const int* in_sizes, int n_in,
                              void* d_out, int out_size, void* d_ws, size_t ws_size,
                              hipStream_t stream) {
    const float* x       = (const float*)d_in[0];
    const float* im_feat = (const float*)d_in[1];
    const float* pos_w   = (const float*)d_in[2];
    const float* pos_b   = (const float*)d_in[3];
    float* out = (float*)d_out;

    float* Rws = (float*)d_ws;                       // 8 * 16 floats
    const size_t XT_OFF = 1024;                      // keeps xt 16B-aligned
    size_t need = XT_OFF + (size_t)8 * DHW * 8 + 64; // fp16-packed xt + pad

    compute_R_kernel<<<8, 64, 0, stream>>>(im_feat, pos_w, pos_b, Rws);

    int total = 8 * DHW;
    if (ws_size >= need) {
        uint2* xt = (uint2*)((char*)d_ws + XT_OFF);
        transpose_pack_kernel<<<total / 256, 256, 0, stream>>>(x, xt);
        sample_kernel_h<<<total / 256, 256, 0, stream>>>((const char*)xt, Rws, out);
    } else {
        sample_kernel<<<total / 256, 256, 0, stream>>>(x, Rws, out);
    }
}